// Round 6
// baseline (351.510 us; speedup 1.0000x reference)
//
#include <hip/hip_runtime.h>
#include <hip/hip_cooperative_groups.h>
#include <hip/hip_fp16.h>
#include <math.h>

namespace cg = cooperative_groups;

// Problem constants (B=8, S=2048, T=128)
#define S_LEN 2048
#define T_DIM 128
#define BM 128               // tokens per block (m-range)
#define NBLK 256             // (mb 0..127) x (ph 0..1) == #CUs -> 1 block/CU (coop)
#define CAP 32               // bucket capacity per output row (Poisson lambda=1)
#define P_ELEMS (16384u * 128u)  // one ph-half partial plane, f16 elements

typedef _Float16 half8 __attribute__((ext_vector_type(8)));
typedef _Float16 half4 __attribute__((ext_vector_type(4)));
typedef float floatx16 __attribute__((ext_vector_type(16)));

// ---------------------------------------------------------------------------
// Single cooperative kernel, 3 grid-synced phases:
//  P1: W fp32 [t][p][q] -> W16f fp16 MFMA-fragment order; zero bucket counters
//  P2: MFMA GEMM (R5 structure: BM=128, p-split ph=blk&1 == XCD parity,
//      8 waves (th x2, kh x4), barrier-free p-loop, 4-phase kh LDS reduction,
//      f16 partial planes P[ph]) + bucket-fill of token->head lists
//  P3: gather: out[b,i,t] = Sw*tanh(bc)+br + sum_{m in bucket[b,i]}
//      w_red[s_m]*(tanh(P0[m,t]+P1[m,t]+bc) - tanh(bc))   -- plain stores,
//      no output atomics, init kernel absorbed.
// v_mfma_f32_32x32x16_f16: A lane m=l&31, k=(l>>5)*8+j; B n=l&31 same k;
// C/D col=l&31, row=(r&3)+8*(r>>2)+4*(l>>5)   [m74/m101-verified]
// ---------------------------------------------------------------------------
__global__ __launch_bounds__(512, 2) void fused_kernel(
    const float* __restrict__ tok, const int* __restrict__ heads,
    const float* __restrict__ W, const float* __restrict__ b_comp,
    const float* __restrict__ w_red, const float* __restrict__ b_red,
    _Float16* __restrict__ W16f, _Float16* __restrict__ P,
    int* __restrict__ count, unsigned short* __restrict__ bucket,
    float* __restrict__ out) {
  __shared__ _Float16 tokT2[64 * 128];   // 16 KB: [p_local][(m&31)*4 + (m>>5)]
  __shared__ float red[128 * 128];       // 64 KB: kh-reduction plane [m][t]
  __shared__ float bcs[128], tbcs[128];  // phase-3 tables
  __shared__ float swred[8];

  const int tid = threadIdx.x;
  const int lane = tid & 63;
  const int wave = tid >> 6;  // 0..7
  const int l31 = lane & 31;
  const int lh = lane >> 5;
  const int blk = blockIdx.x;
  cg::grid_group grid = cg::this_grid();

  // ==================== PHASE 1: convert W + zero counters ====================
  {
    const int t = blk >> 1, qh = blk & 1;
    const int tc = t >> 5, tl = t & 31;
#pragma unroll
    for (int it = 0; it < 2; ++it) {
      const int e8 = it * 512 + tid;     // 0..1023 over [p(128)][q-chunk(8)]
      const int p = e8 >> 3;
      const int q = qh * 64 + (e8 & 7) * 8;
      const float* src = W + (size_t)t * 16384 + (size_t)p * 128 + q;
      const float4 v0 = *(const float4*)src;
      const float4 v1 = *(const float4*)(src + 4);
      half8 h;
      h[0] = (_Float16)v0.x; h[1] = (_Float16)v0.y;
      h[2] = (_Float16)v0.z; h[3] = (_Float16)v0.w;
      h[4] = (_Float16)v1.x; h[5] = (_Float16)v1.y;
      h[6] = (_Float16)v1.z; h[7] = (_Float16)v1.w;
      const int kc = q >> 4, lh2 = (q >> 3) & 1;
      *(half8*)(W16f + ((size_t)((p * 4 + tc) * 8 + kc)) * 512 + lh2 * 256 + tl * 8) = h;
    }
    if (tid < 64) count[blk * 64 + tid] = 0;
  }
  __threadfence();
  grid.sync();

  // ==================== PHASE 2: MFMA GEMM + bucket fill ====================
  {
    const int ph = blk & 1;     // p-half, == XCD parity
    const int mb = blk >> 1;    // 0..127
    const int th = wave & 1;    // t-half
    const int kh = wave >> 1;   // q-quarter
    const size_t tokbase = (size_t)mb * BM * T_DIM;

    // bucket-fill: ph==0 blocks register their 128 tokens (overlaps p-loop)
    if (ph == 0 && tid < BM) {
      const int m = mb * BM + tid;
      const int row = (m >> 11) * S_LEN + heads[m];
      const int pos = atomicAdd(&count[row], 1);
      if (pos < CAP) bucket[row * CAP + pos] = (unsigned short)m;
    }

    // stage tokT2: tok[m, ph*64 + p] as f16, mh-packed for ds_read_b64
#pragma unroll
    for (int it = 0; it < 4; ++it) {
      const int f = it * 512 + tid;   // 0..2047 over [m(128)][p4(16)]
      const int m = f >> 4;
      const int p0 = (f & 15) * 4;
      const float4 v = *(const float4*)(tok + tokbase + (size_t)m * 128 + ph * 64 + p0);
      const int mi = (m & 31) * 4 + (m >> 5);
      tokT2[(p0 + 0) * 128 + mi] = (_Float16)v.x;
      tokT2[(p0 + 1) * 128 + mi] = (_Float16)v.y;
      tokT2[(p0 + 2) * 128 + mi] = (_Float16)v.z;
      tokT2[(p0 + 3) * 128 + mi] = (_Float16)v.w;
    }

    // per-lane h fragments: h16[mh][ks], q0 = kh*32 + ks*16 + lh*8
    half8 h16[4][2];
#pragma unroll
    for (int mh = 0; mh < 4; ++mh) {
      const int m = mh * 32 + l31;
#pragma unroll
      for (int ks = 0; ks < 2; ++ks) {
        const int q0 = kh * 32 + ks * 16 + lh * 8;
        const float4 v0 = *(const float4*)(tok + tokbase + (size_t)m * 128 + q0);
        const float4 v1 = *(const float4*)(tok + tokbase + (size_t)m * 128 + q0 + 4);
        h16[mh][ks][0] = (_Float16)tanhf(v0.x);
        h16[mh][ks][1] = (_Float16)tanhf(v0.y);
        h16[mh][ks][2] = (_Float16)tanhf(v0.z);
        h16[mh][ks][3] = (_Float16)tanhf(v0.w);
        h16[mh][ks][4] = (_Float16)tanhf(v1.x);
        h16[mh][ks][5] = (_Float16)tanhf(v1.y);
        h16[mh][ks][6] = (_Float16)tanhf(v1.z);
        h16[mh][ks][7] = (_Float16)tanhf(v1.w);
      }
    }
    __syncthreads();  // tokT2 ready

    int off[2][2];
#pragma unroll
    for (int tt = 0; tt < 2; ++tt)
#pragma unroll
      for (int ks = 0; ks < 2; ++ks)
        off[tt][ks] = (((th * 2 + tt) * 8 + kh * 2 + ks) << 9) + lane * 8;

    floatx16 acc[4][2];  // [mh][tt]
#pragma unroll
    for (int mh = 0; mh < 4; ++mh)
#pragma unroll
      for (int tt = 0; tt < 2; ++tt)
#pragma unroll
        for (int r = 0; r < 16; ++r) acc[mh][tt][r] = 0.f;

    half8 bf0[2][2], bf1[2][2];
    const _Float16* Wbase = W16f + (size_t)ph * 64 * 16384;

    auto loadB = [&](half8 (&bf)[2][2], int p) {
      const _Float16* wp = Wbase + (size_t)p * 16384;
#pragma unroll
      for (int tt = 0; tt < 2; ++tt)
#pragma unroll
        for (int ks = 0; ks < 2; ++ks)
          bf[tt][ks] = *(const half8*)(wp + off[tt][ks]);
    };

    auto compute = [&](half8 (&bf)[2][2], half4 tk) {
#pragma unroll
      for (int ks = 0; ks < 2; ++ks) {
        half8 a0 = h16[0][ks] * tk[0];
        half8 a1 = h16[1][ks] * tk[1];
        half8 a2 = h16[2][ks] * tk[2];
        half8 a3 = h16[3][ks] * tk[3];
        acc[0][0] = __builtin_amdgcn_mfma_f32_32x32x16_f16(a0, bf[0][ks], acc[0][0], 0, 0, 0);
        acc[0][1] = __builtin_amdgcn_mfma_f32_32x32x16_f16(a0, bf[1][ks], acc[0][1], 0, 0, 0);
        acc[1][0] = __builtin_amdgcn_mfma_f32_32x32x16_f16(a1, bf[0][ks], acc[1][0], 0, 0, 0);
        acc[1][1] = __builtin_amdgcn_mfma_f32_32x32x16_f16(a1, bf[1][ks], acc[1][1], 0, 0, 0);
        acc[2][0] = __builtin_amdgcn_mfma_f32_32x32x16_f16(a2, bf[0][ks], acc[2][0], 0, 0, 0);
        acc[2][1] = __builtin_amdgcn_mfma_f32_32x32x16_f16(a2, bf[1][ks], acc[2][1], 0, 0, 0);
        acc[3][0] = __builtin_amdgcn_mfma_f32_32x32x16_f16(a3, bf[0][ks], acc[3][0], 0, 0, 0);
        acc[3][1] = __builtin_amdgcn_mfma_f32_32x32x16_f16(a3, bf[1][ks], acc[3][1], 0, 0, 0);
      }
    };

    // barrier-free software-pipelined p-loop (tk prefetched 1 iter ahead)
    half4 tkc = *(const half4*)(tokT2 + l31 * 4);
    loadB(bf0, 0);
    for (int p = 0; p < 64; p += 2) {
      loadB(bf1, p + 1);
      const half4 tkn = *(const half4*)(tokT2 + (p + 1) * 128 + l31 * 4);
      compute(bf0, tkc);
      half4 tkc2 = tkn;
      if (p + 2 < 64) {
        loadB(bf0, p + 2);
        tkc = *(const half4*)(tokT2 + (p + 2) * 128 + l31 * 4);
      }
      compute(bf1, tkc2);
    }

    // serial 4-phase kh reduction in LDS (stride 128: <=2-way alias, free)
    __syncthreads();
#pragma unroll
    for (int phase = 0; phase < 4; ++phase) {
      if (kh == phase) {
#pragma unroll
        for (int mh = 0; mh < 4; ++mh)
#pragma unroll
          for (int tt = 0; tt < 2; ++tt) {
            const int tcol = (th * 2 + tt) * 32 + l31;
#pragma unroll
            for (int r = 0; r < 16; ++r) {
              const int m_loc = (r & 3) + 8 * (r >> 2) + 4 * lh;
              const int addr = (mh * 32 + m_loc) * 128 + tcol;
              if (phase == 0) red[addr] = acc[mh][tt][r];
              else            red[addr] += acc[mh][tt][r];
            }
          }
      }
      __syncthreads();
    }

    // cooperative f16 store of this block's partial plane
    _Float16* Pp = P + (size_t)ph * P_ELEMS;
#pragma unroll
    for (int it = 0; it < 4; ++it) {
      const int chunk = it * 512 + tid;  // [m(128)][t-chunk(16)]
      const int m = chunk >> 4;
      const int t0 = (chunk & 15) * 8;
      const float4 a = *(const float4*)&red[m * 128 + t0];
      const float4 b = *(const float4*)&red[m * 128 + t0 + 4];
      half8 h;
      h[0] = (_Float16)a.x; h[1] = (_Float16)a.y;
      h[2] = (_Float16)a.z; h[3] = (_Float16)a.w;
      h[4] = (_Float16)b.x; h[5] = (_Float16)b.y;
      h[6] = (_Float16)b.z; h[7] = (_Float16)b.w;
      *(half8*)(Pp + (size_t)(mb * BM + m) * 128 + t0) = h;
    }
  }
  __threadfence();
  grid.sync();

  // ==================== PHASE 3: gather + store (no atomics) ====================
  {
    // per-block sum(w_red) reduction + bc/tanh(bc) tables
    const float4 wv = *(const float4*)(w_red + tid * 4);
    float part = wv.x + wv.y + wv.z + wv.w;
#pragma unroll
    for (int o = 32; o > 0; o >>= 1) part += __shfl_down(part, o, 64);
    if (lane == 0) swred[wave] = part;
    if (tid < 128) {
      bcs[tid] = b_comp[tid];
      tbcs[tid] = tanhf(bcs[tid]);
    }
    __syncthreads();
    float Sw = 0.f;
#pragma unroll
    for (int w = 0; w < 8; ++w) Sw += swred[w];
    const float br = b_red[0];

    const int t = tid & 127;
    const int rlane = tid >> 7;  // 4 rows in parallel
    const float bc = bcs[t];
    const float tbc = tbcs[t];
    const float base = Sw * tbc + br;
#pragma unroll 2
    for (int it = 0; it < 16; ++it) {
      const int row = blk * 64 + it * 4 + rlane;  // (b*S + i)
      int cnt = count[row];
      cnt = cnt < CAP ? cnt : CAP;
      float acc = base;
      for (int c = 0; c < cnt; ++c) {
        const int m = bucket[row * CAP + c];
        const float wr = w_red[m & 2047];
        const float v = (float)P[(size_t)m * 128 + t] +
                        (float)P[P_ELEMS + (size_t)m * 128 + t] + bc;
        acc += wr * (tanhf(v) - tbc);
      }
      out[(size_t)row * 128 + t] = acc;
    }
  }
}

// ---------------------------------------------------------------------------
extern "C" void kernel_launch(void* const* d_in, const int* in_sizes, int n_in,
                              void* d_out, int out_size, void* d_ws, size_t ws_size,
                              hipStream_t stream) {
  const float* tok    = (const float*)d_in[0];
  // d_in[1] = dep_embeddings: dead input (source bug), unused
  const int*   heads  = (const int*)d_in[2];
  const float* W      = (const float*)d_in[3];
  const float* b_comp = (const float*)d_in[4];
  const float* w_red  = (const float*)d_in[5];
  const float* b_red  = (const float*)d_in[6];
  float* out = (float*)d_out;

  // ws layout: W16f 4MB | P 8MB | count 64KB | bucket 1MB  (~13.1 MB)
  char* ws = (char*)d_ws;
  _Float16* W16f        = (_Float16*)ws;
  _Float16* P           = (_Float16*)(ws + (4u << 20));
  int* count            = (int*)(ws + (12u << 20));
  unsigned short* bucket = (unsigned short*)(ws + (12u << 20) + (64u << 10));

  void* args[] = {(void*)&tok, (void*)&heads, (void*)&W, (void*)&b_comp,
                  (void*)&w_red, (void*)&b_red, (void*)&W16f, (void*)&P,
                  (void*)&count, (void*)&bucket, (void*)&out};
  hipLaunchCooperativeKernel((const void*)fused_kernel, dim3(NBLK), dim3(512),
                             args, 0, stream);
}

// Round 7
// 235.513 us; speedup vs baseline: 1.4925x; 1.4925x over previous
//
#include <hip/hip_runtime.h>
#include <hip/hip_fp16.h>
#include <math.h>

// Problem constants (B=8, S=2048, T=128)
#define S_LEN 2048
#define T_DIM 128
#define BM 128               // tokens per block (m-range)
#define NBLK 256             // (mb 0..127) x (ph 0..1)
#define P_ELEMS (16384u * 128u)  // one ph-half partial plane, f16 elements

typedef _Float16 half8 __attribute__((ext_vector_type(8)));
typedef _Float16 half4 __attribute__((ext_vector_type(4)));
typedef _Float16 half2t __attribute__((ext_vector_type(2)));
typedef float floatx16 __attribute__((ext_vector_type(16)));

// ---------------------------------------------------------------------------
// Kernel A (grid 2304x256): fused prep, independent block ranges:
//  blocks 0..255   : W fp32 [t][p][q] -> W16f fp16 MFMA-fragment order
//                    (blocks 0..127 also zero flag[mb])
//  blocks 256..2303: out[b,i,t] = sum(w_red)*tanh(b_comp[t]) + b_red
// ---------------------------------------------------------------------------
__global__ __launch_bounds__(256) void prep_kernel(
    const float* __restrict__ W, const float* __restrict__ w_red,
    const float* __restrict__ b_comp, const float* __restrict__ b_red,
    _Float16* __restrict__ W16f, int* __restrict__ flag,
    float* __restrict__ out) {
  const int blk = blockIdx.x;
  const int tid = threadIdx.x;
  if (blk < 256) {
    if (blk < 128 && tid == 0) flag[blk] = 0;
    const int t = blk >> 1, qh = blk & 1;
    const int tc = t >> 5, tl = t & 31;
#pragma unroll
    for (int it = 0; it < 4; ++it) {
      const int e8 = it * 256 + tid;        // 0..1023 over [p(128)][q-chunk(8)]
      const int p = e8 >> 3;
      const int q = qh * 64 + (e8 & 7) * 8;
      const float* src = W + (size_t)t * 16384 + (size_t)p * 128 + q;
      const float4 v0 = *(const float4*)src;
      const float4 v1 = *(const float4*)(src + 4);
      half8 h;
      h[0] = (_Float16)v0.x; h[1] = (_Float16)v0.y;
      h[2] = (_Float16)v0.z; h[3] = (_Float16)v0.w;
      h[4] = (_Float16)v1.x; h[5] = (_Float16)v1.y;
      h[6] = (_Float16)v1.z; h[7] = (_Float16)v1.w;
      const int kc = q >> 4, lh2 = (q >> 3) & 1;
      *(half8*)(W16f + ((size_t)((p * 4 + tc) * 8 + kc)) * 512 + lh2 * 256 + tl * 8) = h;
    }
  } else {
    __shared__ float red4[4];
    float part = 0.f;
#pragma unroll
    for (int i = 0; i < 8; ++i) part += w_red[tid * 8 + i];
#pragma unroll
    for (int off = 32; off > 0; off >>= 1) part += __shfl_down(part, off, 64);
    if ((tid & 63) == 0) red4[tid >> 6] = part;
    __syncthreads();
    const float Sw = red4[0] + red4[1] + red4[2] + red4[3];
    const float br = b_red[0];
    const size_t base = (size_t)(blk - 256) * 1024 + (size_t)tid * 4;
    const int t0 = (int)(base & 127);
    float4 v;
    v.x = Sw * tanhf(b_comp[t0 + 0]) + br;
    v.y = Sw * tanhf(b_comp[t0 + 1]) + br;
    v.z = Sw * tanhf(b_comp[t0 + 2]) + br;
    v.w = Sw * tanhf(b_comp[t0 + 3]) + br;
    *(float4*)(out + base) = v;
  }
}

// ---------------------------------------------------------------------------
// Kernel B: MFMA main. Block = (mb = blk>>1, ph = blk&1); ph == XCD parity
// -> each XCD's blocks read the SAME contiguous 2MB half of W16f (L2-resident).
// 8 waves = (th x2, kh x4), each covering all 4 m-tiles -> zero B redundancy.
// Barrier-free p-loop, 3-buffer distance-2 prefetch. 4-phase kh LDS reduction.
// Pairwise epilogue: both blocks store f16 planes; the SECOND finisher of each
// mb pair (flag atomic) combines partner plane + own LDS f32 partials, tanh,
// scatter-atomicAdd to out. No grid sync, no separate epilogue kernel.
// v_mfma_f32_32x32x16_f16: A lane m=l&31, k=(l>>5)*8+j; B n=l&31 same k;
// C/D col=l&31, row=(r&3)+8*(r>>2)+4*(l>>5)   [m74/m101-verified]
// ---------------------------------------------------------------------------
__global__ __launch_bounds__(512, 2) void main_kernel(
    const float* __restrict__ tok, const int* __restrict__ heads,
    const _Float16* __restrict__ W16f, const float* __restrict__ b_comp,
    const float* __restrict__ w_red, _Float16* __restrict__ P,
    int* __restrict__ flag, float* __restrict__ out) {
  __shared__ _Float16 tokT2[64 * 128];   // 16 KB: [p_local][(m&31)*4 + (m>>5)]
  __shared__ float red[128 * 128];       // 64 KB: kh-reduction plane [m][t]
  __shared__ int amSecond;

  const int tid = threadIdx.x;
  const int lane = tid & 63;
  const int wave = tid >> 6;  // 0..7
  const int th = wave & 1;    // t-half (64 cols)
  const int kh = wave >> 1;   // q-quarter (32 of 128)
  const int l31 = lane & 31;
  const int lh = lane >> 5;
  const int blk = blockIdx.x;
  const int ph = blk & 1;     // p-half, == XCD parity
  const int mb = blk >> 1;    // 0..127
  const size_t tokbase = (size_t)mb * BM * T_DIM;

  // ---- stage tokT2: tok[m, ph*64 + p] as f16, mh-packed for ds_read_b64 ----
#pragma unroll
  for (int it = 0; it < 4; ++it) {
    const int f = it * 512 + tid;   // 0..2047 over [m(128)][p4(16)]
    const int m = f >> 4;
    const int p0 = (f & 15) * 4;
    const float4 v = *(const float4*)(tok + tokbase + (size_t)m * 128 + ph * 64 + p0);
    const int mi = (m & 31) * 4 + (m >> 5);
    tokT2[(p0 + 0) * 128 + mi] = (_Float16)v.x;
    tokT2[(p0 + 1) * 128 + mi] = (_Float16)v.y;
    tokT2[(p0 + 2) * 128 + mi] = (_Float16)v.z;
    tokT2[(p0 + 3) * 128 + mi] = (_Float16)v.w;
  }

  // ---- per-lane h fragments: h16[mh][ks], q0 = kh*32 + ks*16 + lh*8 ----
  half8 h16[4][2];
#pragma unroll
  for (int mh = 0; mh < 4; ++mh) {
    const int m = mh * 32 + l31;
#pragma unroll
    for (int ks = 0; ks < 2; ++ks) {
      const int q0 = kh * 32 + ks * 16 + lh * 8;
      const float4 v0 = *(const float4*)(tok + tokbase + (size_t)m * 128 + q0);
      const float4 v1 = *(const float4*)(tok + tokbase + (size_t)m * 128 + q0 + 4);
      h16[mh][ks][0] = (_Float16)tanhf(v0.x);
      h16[mh][ks][1] = (_Float16)tanhf(v0.y);
      h16[mh][ks][2] = (_Float16)tanhf(v0.z);
      h16[mh][ks][3] = (_Float16)tanhf(v0.w);
      h16[mh][ks][4] = (_Float16)tanhf(v1.x);
      h16[mh][ks][5] = (_Float16)tanhf(v1.y);
      h16[mh][ks][6] = (_Float16)tanhf(v1.z);
      h16[mh][ks][7] = (_Float16)tanhf(v1.w);
    }
  }
  __syncthreads();  // tokT2 ready

  int off[2][2];
#pragma unroll
  for (int tt = 0; tt < 2; ++tt)
#pragma unroll
    for (int ks = 0; ks < 2; ++ks)
      off[tt][ks] = (((th * 2 + tt) * 8 + kh * 2 + ks) << 9) + lane * 8;

  floatx16 acc[4][2];  // [mh][tt]
#pragma unroll
  for (int mh = 0; mh < 4; ++mh)
#pragma unroll
    for (int tt = 0; tt < 2; ++tt)
#pragma unroll
      for (int r = 0; r < 16; ++r) acc[mh][tt][r] = 0.f;

  half8 bf0[2][2], bf1[2][2], bf2[2][2];
  const _Float16* Wbase = W16f + (size_t)ph * 64 * 16384;

  auto loadB = [&](half8 (&bf)[2][2], int p) {
    const _Float16* wp = Wbase + (size_t)p * 16384;
#pragma unroll
    for (int tt = 0; tt < 2; ++tt)
#pragma unroll
      for (int ks = 0; ks < 2; ++ks)
        bf[tt][ks] = *(const half8*)(wp + off[tt][ks]);
  };

  auto compute = [&](half8 (&bf)[2][2], int p) {
    const half4 tk = *(const half4*)(tokT2 + p * 128 + l31 * 4);
#pragma unroll
    for (int ks = 0; ks < 2; ++ks) {
      half8 a0 = h16[0][ks] * tk[0];
      half8 a1 = h16[1][ks] * tk[1];
      half8 a2 = h16[2][ks] * tk[2];
      half8 a3 = h16[3][ks] * tk[3];
      acc[0][0] = __builtin_amdgcn_mfma_f32_32x32x16_f16(a0, bf[0][ks], acc[0][0], 0, 0, 0);
      acc[0][1] = __builtin_amdgcn_mfma_f32_32x32x16_f16(a0, bf[1][ks], acc[0][1], 0, 0, 0);
      acc[1][0] = __builtin_amdgcn_mfma_f32_32x32x16_f16(a1, bf[0][ks], acc[1][0], 0, 0, 0);
      acc[1][1] = __builtin_amdgcn_mfma_f32_32x32x16_f16(a1, bf[1][ks], acc[1][1], 0, 0, 0);
      acc[2][0] = __builtin_amdgcn_mfma_f32_32x32x16_f16(a2, bf[0][ks], acc[2][0], 0, 0, 0);
      acc[2][1] = __builtin_amdgcn_mfma_f32_32x32x16_f16(a2, bf[1][ks], acc[2][1], 0, 0, 0);
      acc[3][0] = __builtin_amdgcn_mfma_f32_32x32x16_f16(a3, bf[0][ks], acc[3][0], 0, 0, 0);
      acc[3][1] = __builtin_amdgcn_mfma_f32_32x32x16_f16(a3, bf[1][ks], acc[3][1], 0, 0, 0);
    }
  };

  // 3-buffer, distance-2 software pipeline (no barriers).
  // Invariant at top of each iter: bf0 = p, bf1 = p+1.
  loadB(bf0, 0);
  loadB(bf1, 1);
  for (int p = 0; p < 60; p += 3) {
    loadB(bf2, p + 2);
    compute(bf0, p);
    loadB(bf0, p + 3);
    compute(bf1, p + 1);
    loadB(bf1, p + 4);
    compute(bf2, p + 2);
  }
  // p = 60: bf0=60, bf1=61
  loadB(bf2, 62);
  compute(bf0, 60);
  loadB(bf0, 63);
  compute(bf1, 61);
  compute(bf2, 62);
  compute(bf0, 63);

  // ---- serial 4-phase kh reduction in LDS (stride 128: 2-way alias = free) ----
  __syncthreads();
#pragma unroll
  for (int phase = 0; phase < 4; ++phase) {
    if (kh == phase) {
#pragma unroll
      for (int mh = 0; mh < 4; ++mh)
#pragma unroll
        for (int tt = 0; tt < 2; ++tt) {
          const int tcol = (th * 2 + tt) * 32 + l31;
#pragma unroll
          for (int r = 0; r < 16; ++r) {
            const int m_loc = (r & 3) + 8 * (r >> 2) + 4 * lh;
            const int addr = (mh * 32 + m_loc) * 128 + tcol;
            if (phase == 0) red[addr] = acc[mh][tt][r];
            else            red[addr] += acc[mh][tt][r];
          }
        }
    }
    __syncthreads();
  }

  // ---- store this block's f16 partial plane ----
  _Float16* Pp = P + (size_t)ph * P_ELEMS;
#pragma unroll
  for (int it = 0; it < 4; ++it) {
    const int chunk = it * 512 + tid;  // [m(128)][t-chunk(16)]
    const int m = chunk >> 4;
    const int t0 = (chunk & 15) * 8;
    const float4 a = *(const float4*)&red[m * 128 + t0];
    const float4 b = *(const float4*)&red[m * 128 + t0 + 4];
    half8 h;
    h[0] = (_Float16)a.x; h[1] = (_Float16)a.y;
    h[2] = (_Float16)a.z; h[3] = (_Float16)a.w;
    h[4] = (_Float16)b.x; h[5] = (_Float16)b.y;
    h[6] = (_Float16)b.z; h[7] = (_Float16)b.w;
    *(half8*)(Pp + (size_t)(mb * BM + m) * 128 + t0) = h;
  }

  // ---- pairwise release/acquire: second finisher does the epilogue ----
  __threadfence();   // release: plane stores visible device-wide
  __syncthreads();   // all threads' fences done before the atomic
  if (tid == 0) amSecond = (atomicAdd(&flag[mb], 1) == 1);
  __syncthreads();
  if (amSecond) {
    __threadfence();  // acquire
    const _Float16* Ppart =
        P + (size_t)(ph ^ 1) * P_ELEMS + (size_t)mb * BM * 128;
    const int t0 = (tid & 63) * 2;
    const int mg = tid >> 6;  // == wave: heads/w_red loads wave-uniform
    const float bc0 = b_comp[t0], bc1 = b_comp[t0 + 1];
    const float tb0 = tanhf(bc0), tb1 = tanhf(bc1);
#pragma unroll 2
    for (int mi = 0; mi < 16; ++mi) {
      const int m_loc = mi * 8 + mg;
      const int gm = mb * BM + m_loc;
      const int head = heads[gm];
      const float wr = w_red[gm & 2047];
      const half2t pp = *(const half2t*)(Ppart + m_loc * 128 + t0);
      const float v0 = red[m_loc * 128 + t0]     + (float)pp[0] + bc0;
      const float v1 = red[m_loc * 128 + t0 + 1] + (float)pp[1] + bc1;
      float* orow = out + ((size_t)(gm >> 11) * S_LEN + head) * T_DIM;
      atomicAdd(orow + t0,     wr * (tanhf(v0) - tb0));
      atomicAdd(orow + t0 + 1, wr * (tanhf(v1) - tb1));
    }
  }
}

// ---------------------------------------------------------------------------
extern "C" void kernel_launch(void* const* d_in, const int* in_sizes, int n_in,
                              void* d_out, int out_size, void* d_ws, size_t ws_size,
                              hipStream_t stream) {
  const float* tok    = (const float*)d_in[0];
  // d_in[1] = dep_embeddings: dead input (source bug), unused
  const int*   heads  = (const int*)d_in[2];
  const float* W      = (const float*)d_in[3];
  const float* b_comp = (const float*)d_in[4];
  const float* w_red  = (const float*)d_in[5];
  const float* b_red  = (const float*)d_in[6];
  float* out = (float*)d_out;

  // ws layout: W16f 4MB | P 8MB | flag 512B
  char* ws = (char*)d_ws;
  _Float16* W16f = (_Float16*)ws;
  _Float16* P    = (_Float16*)(ws + (4u << 20));
  int* flag      = (int*)(ws + (12u << 20));

  prep_kernel<<<2304, 256, 0, stream>>>(W, w_red, b_comp, b_red, W16f, flag, out);
  main_kernel<<<NBLK, 512, 0, stream>>>(tok, heads, W16f, b_comp, w_red, P, flag, out);
}

// Round 8
// 169.154 us; speedup vs baseline: 2.0780x; 1.3923x over previous
//
#include <hip/hip_runtime.h>
#include <hip/hip_fp16.h>
#include <math.h>

// Problem constants (B=8, S=2048, T=128)
#define S_LEN 2048
#define T_DIM 128
#define BM 128               // tokens per block (m-range)
#define NBLK 256             // (mb 0..127) x (th-half 0..1)

typedef _Float16 half8 __attribute__((ext_vector_type(8)));
typedef _Float16 half4 __attribute__((ext_vector_type(4)));
typedef float floatx16 __attribute__((ext_vector_type(16)));

// ---------------------------------------------------------------------------
// Kernel A (grid 2304x256): fused prep, independent block ranges:
//  blocks 0..255   : W fp32 [t][p][q] -> W16f fp16 MFMA-fragment order
//    W16f[((p*4 + tc)*8 + kc)*512 + lh2*256 + (t&31)*8 + j],
//    tc=t>>5, kc=q>>4, lh2=(q>>3)&1, j=q&7
//  blocks 256..2303: out[b,i,t] = sum(w_red)*tanh(b_comp[t]) + b_red
// ---------------------------------------------------------------------------
__global__ __launch_bounds__(256) void prep_kernel(
    const float* __restrict__ W, const float* __restrict__ w_red,
    const float* __restrict__ b_comp, const float* __restrict__ b_red,
    _Float16* __restrict__ W16f, float* __restrict__ out) {
  const int blk = blockIdx.x;
  const int tid = threadIdx.x;
  if (blk < 256) {
    const int t = blk >> 1, qh = blk & 1;
    const int tc = t >> 5, tl = t & 31;
#pragma unroll
    for (int it = 0; it < 4; ++it) {
      const int e8 = it * 256 + tid;        // 0..1023 over [p(128)][q-chunk(8)]
      const int p = e8 >> 3;
      const int q = qh * 64 + (e8 & 7) * 8;
      const float* src = W + (size_t)t * 16384 + (size_t)p * 128 + q;
      const float4 v0 = *(const float4*)src;
      const float4 v1 = *(const float4*)(src + 4);
      half8 h;
      h[0] = (_Float16)v0.x; h[1] = (_Float16)v0.y;
      h[2] = (_Float16)v0.z; h[3] = (_Float16)v0.w;
      h[4] = (_Float16)v1.x; h[5] = (_Float16)v1.y;
      h[6] = (_Float16)v1.z; h[7] = (_Float16)v1.w;
      const int kc = q >> 4, lh2 = (q >> 3) & 1;
      *(half8*)(W16f + ((size_t)((p * 4 + tc) * 8 + kc)) * 512 + lh2 * 256 + tl * 8) = h;
    }
  } else {
    __shared__ float red4[4];
    float part = 0.f;
#pragma unroll
    for (int i = 0; i < 8; ++i) part += w_red[tid * 8 + i];
#pragma unroll
    for (int off = 32; off > 0; off >>= 1) part += __shfl_down(part, off, 64);
    if ((tid & 63) == 0) red4[tid >> 6] = part;
    __syncthreads();
    const float Sw = red4[0] + red4[1] + red4[2] + red4[3];
    const float br = b_red[0];
    const size_t base = (size_t)(blk - 256) * 1024 + (size_t)tid * 4;
    const int t0 = (int)(base & 127);
    float4 v;
    v.x = Sw * tanhf(b_comp[t0 + 0]) + br;
    v.y = Sw * tanhf(b_comp[t0 + 1]) + br;
    v.z = Sw * tanhf(b_comp[t0 + 2]) + br;
    v.w = Sw * tanhf(b_comp[t0 + 3]) + br;
    *(float4*)(out + base) = v;
  }
}

// ---------------------------------------------------------------------------
// Kernel B: MFMA main, N-SPLIT (not K-split). Block = (mb = blk>>1, thb = blk&1).
// BM=128 tokens x TN=64 output cols, FULL K=16384 per block -> block owns the
// complete val for its tile: in-LDS kh-reduction + inline scatter epilogue.
// No partial planes, no cross-block sync. thb == XCD parity -> each XCD's
// blocks read the same 2MB of W16f fragments (L2-resident); B traffic 0.5 GB.
// 8 waves = (th: t-tile-of-32 x2, kh: q-quarter x4); each wave covers all 4
// m-tiles; 2 coalesced 1KB B-loads + 8 MFMA per p; barrier-free p-loop with
// 3-buffer distance-2 prefetch. acc = 4 x floatx16 = 64 AGPRs.
// v_mfma_f32_32x32x16_f16: A lane m=l&31, k=(l>>5)*8+j; B n=l&31 same k;
// C/D col=l&31, row=(r&3)+8*(r>>2)+4*(l>>5)   [m74/m101-verified]
// ---------------------------------------------------------------------------
__global__ __launch_bounds__(512, 2) void main_kernel(
    const float* __restrict__ tok, const int* __restrict__ heads,
    const _Float16* __restrict__ W16f, const float* __restrict__ b_comp,
    const float* __restrict__ w_red, float* __restrict__ out) {
  __shared__ _Float16 tokT2[128 * 128];  // 32 KB: [p][(m&31)*4 + (m>>5)]
  __shared__ float red[128 * 64];        // 32 KB: [m][t_loc] full-val plane

  const int tid = threadIdx.x;
  const int lane = tid & 63;
  const int wave = tid >> 6;  // 0..7
  const int th = wave & 1;    // t-tile (32 cols) within the block's 64-half
  const int kh = wave >> 1;   // q-quarter (32 of 128)
  const int l31 = lane & 31;
  const int lh = lane >> 5;
  const int blk = blockIdx.x;
  const int thb = blk & 1;    // t-half of the output, == XCD parity
  const int mb = blk >> 1;    // 0..127
  const size_t tokbase = (size_t)mb * BM * T_DIM;

  // ---- stage tokT2: all 128 p, mh-packed for half4 ds_read ----
#pragma unroll
  for (int it = 0; it < 8; ++it) {
    const int f = it * 512 + tid;   // 0..4095 float4s over [m(128)][p4(32)]
    const int m = f >> 5;
    const int p0 = (f & 31) * 4;
    const float4 v = *(const float4*)(tok + tokbase + (size_t)m * 128 + p0);
    const int mi = (m & 31) * 4 + (m >> 5);
    tokT2[(p0 + 0) * 128 + mi] = (_Float16)v.x;
    tokT2[(p0 + 1) * 128 + mi] = (_Float16)v.y;
    tokT2[(p0 + 2) * 128 + mi] = (_Float16)v.z;
    tokT2[(p0 + 3) * 128 + mi] = (_Float16)v.w;
  }

  // ---- per-lane h fragments: h16[mh][ks], q0 = kh*32 + ks*16 + lh*8 ----
  half8 h16[4][2];
#pragma unroll
  for (int mh = 0; mh < 4; ++mh) {
    const int m = mh * 32 + l31;
#pragma unroll
    for (int ks = 0; ks < 2; ++ks) {
      const int q0 = kh * 32 + ks * 16 + lh * 8;
      const float4 v0 = *(const float4*)(tok + tokbase + (size_t)m * 128 + q0);
      const float4 v1 = *(const float4*)(tok + tokbase + (size_t)m * 128 + q0 + 4);
      h16[mh][ks][0] = (_Float16)tanhf(v0.x);
      h16[mh][ks][1] = (_Float16)tanhf(v0.y);
      h16[mh][ks][2] = (_Float16)tanhf(v0.z);
      h16[mh][ks][3] = (_Float16)tanhf(v0.w);
      h16[mh][ks][4] = (_Float16)tanhf(v1.x);
      h16[mh][ks][5] = (_Float16)tanhf(v1.y);
      h16[mh][ks][6] = (_Float16)tanhf(v1.z);
      h16[mh][ks][7] = (_Float16)tanhf(v1.w);
    }
  }
  __syncthreads();  // tokT2 ready; last barrier before the p-loop

  // Wave's B-fragment offsets within a p-slice: tc = thb*2 + th, kc = kh*2+ks
  const int tc = thb * 2 + th;
  int off0[2];
#pragma unroll
  for (int ks = 0; ks < 2; ++ks)
    off0[ks] = ((tc * 8 + kh * 2 + ks) << 9) + lane * 8;

  floatx16 acc[4];  // [mh] -> 64 AGPRs
#pragma unroll
  for (int mh = 0; mh < 4; ++mh)
#pragma unroll
    for (int r = 0; r < 16; ++r) acc[mh][r] = 0.f;

  half8 bf0[2], bf1[2], bf2[2];

  auto loadB = [&](half8 (&bf)[2], int p) {
    const _Float16* wp = W16f + (size_t)p * 16384;
#pragma unroll
    for (int ks = 0; ks < 2; ++ks)
      bf[ks] = *(const half8*)(wp + off0[ks]);
  };

  auto compute = [&](half8 (&bf)[2], int p) {
    const half4 tk = *(const half4*)(tokT2 + p * 128 + l31 * 4);
#pragma unroll
    for (int ks = 0; ks < 2; ++ks) {
      half8 a0 = h16[0][ks] * tk[0];
      half8 a1 = h16[1][ks] * tk[1];
      half8 a2 = h16[2][ks] * tk[2];
      half8 a3 = h16[3][ks] * tk[3];
      acc[0] = __builtin_amdgcn_mfma_f32_32x32x16_f16(a0, bf[ks], acc[0], 0, 0, 0);
      acc[1] = __builtin_amdgcn_mfma_f32_32x32x16_f16(a1, bf[ks], acc[1], 0, 0, 0);
      acc[2] = __builtin_amdgcn_mfma_f32_32x32x16_f16(a2, bf[ks], acc[2], 0, 0, 0);
      acc[3] = __builtin_amdgcn_mfma_f32_32x32x16_f16(a3, bf[ks], acc[3], 0, 0, 0);
    }
  };

  // 3-buffer, distance-2 software pipeline over 128 p (no barriers).
  loadB(bf0, 0);
  loadB(bf1, 1);
  for (int p = 0; p < 126; p += 3) {
    loadB(bf2, p + 2);
    compute(bf0, p);
    loadB(bf0, p + 3);
    compute(bf1, p + 1);
    loadB(bf1, p + 4);
    compute(bf2, p + 2);
  }
  compute(bf0, 126);
  compute(bf1, 127);

  // ---- serial 4-phase kh reduction in LDS (stride 64 f32: 2-way = free) ----
  __syncthreads();
#pragma unroll
  for (int phase = 0; phase < 4; ++phase) {
    if (kh == phase) {
#pragma unroll
      for (int mh = 0; mh < 4; ++mh)
#pragma unroll
        for (int r = 0; r < 16; ++r) {
          const int m_loc = (r & 3) + 8 * (r >> 2) + 4 * lh;
          const int addr = (mh * 32 + m_loc) * 64 + th * 32 + l31;
          if (phase == 0) red[addr] = acc[mh][r];
          else            red[addr] += acc[mh][r];
        }
    }
    __syncthreads();
  }

  // ---- inline scatter epilogue: all 512 threads, 16 m's x 1 t each ----
  const int t_loc = tid & 63;
  const int mgrp = tid >> 6;  // 0..7 (wave-uniform -> scalar heads/w_red loads)
  const int t = thb * 64 + t_loc;
  const float bc = b_comp[t];
  const float tb = tanhf(bc);
#pragma unroll 4
  for (int mi = 0; mi < 16; ++mi) {
    const int m_loc = mi * 8 + mgrp;
    const int gm = mb * BM + m_loc;
    const int head = heads[gm];
    const float wr = w_red[gm & 2047];
    const float v = red[m_loc * 64 + t_loc] + bc;
    atomicAdd(out + ((size_t)(gm >> 11) * S_LEN + head) * T_DIM + t,
              wr * (tanhf(v) - tb));
  }
}

// ---------------------------------------------------------------------------
extern "C" void kernel_launch(void* const* d_in, const int* in_sizes, int n_in,
                              void* d_out, int out_size, void* d_ws, size_t ws_size,
                              hipStream_t stream) {
  const float* tok    = (const float*)d_in[0];
  // d_in[1] = dep_embeddings: dead input (source bug), unused
  const int*   heads  = (const int*)d_in[2];
  const float* W      = (const float*)d_in[3];
  const float* b_comp = (const float*)d_in[4];
  const float* w_red  = (const float*)d_in[5];
  const float* b_red  = (const float*)d_in[6];
  float* out = (float*)d_out;

  _Float16* W16f = (_Float16*)d_ws;  // 4 MB, MFMA-fragment order

  prep_kernel<<<2304, 256, 0, stream>>>(W, w_red, b_comp, b_red, W16f, out);
  main_kernel<<<NBLK, 512, 0, stream>>>(tok, heads, W16f, b_comp, w_red, out);
}

// Round 9
// 161.413 us; speedup vs baseline: 2.1777x; 1.0480x over previous
//
#include <hip/hip_runtime.h>
#include <hip/hip_fp16.h>
#include <math.h>

// Problem constants (B=8, S=2048, T=128)
#define S_LEN 2048
#define T_DIM 128
#define BM 128               // tokens per block (m-range)
#define TN 32                // output cols per block
#define NBLK 512             // (mb 0..127) x (tq 0..3), bit-sliced for XCD pinning
#define TOKR 132             // tokT2 row stride in f16 (132*2=264 B: staging 8-way, reads free)

typedef _Float16 half8 __attribute__((ext_vector_type(8)));
typedef _Float16 half4 __attribute__((ext_vector_type(4)));
typedef float floatx16 __attribute__((ext_vector_type(16)));

// ---------------------------------------------------------------------------
// Kernel A (grid 2304x256): fused prep, independent block ranges:
//  blocks 0..255   : W fp32 [t][p][q] -> W16f fp16 MFMA-fragment order
//    W16f[((p*4 + tc)*8 + kc)*512 + lh2*256 + (t&31)*8 + j],
//    tc=t>>5, kc=q>>4, lh2=(q>>3)&1, j=q&7
//  blocks 256..2303: out[b,i,t] = sum(w_red)*tanh(b_comp[t]) + b_red
// ---------------------------------------------------------------------------
__global__ __launch_bounds__(256) void prep_kernel(
    const float* __restrict__ W, const float* __restrict__ w_red,
    const float* __restrict__ b_comp, const float* __restrict__ b_red,
    _Float16* __restrict__ W16f, float* __restrict__ out) {
  const int blk = blockIdx.x;
  const int tid = threadIdx.x;
  if (blk < 256) {
    const int t = blk >> 1, qh = blk & 1;
    const int tc = t >> 5, tl = t & 31;
#pragma unroll
    for (int it = 0; it < 4; ++it) {
      const int e8 = it * 256 + tid;        // 0..1023 over [p(128)][q-chunk(8)]
      const int p = e8 >> 3;
      const int q = qh * 64 + (e8 & 7) * 8;
      const float* src = W + (size_t)t * 16384 + (size_t)p * 128 + q;
      const float4 v0 = *(const float4*)src;
      const float4 v1 = *(const float4*)(src + 4);
      half8 h;
      h[0] = (_Float16)v0.x; h[1] = (_Float16)v0.y;
      h[2] = (_Float16)v0.z; h[3] = (_Float16)v0.w;
      h[4] = (_Float16)v1.x; h[5] = (_Float16)v1.y;
      h[6] = (_Float16)v1.z; h[7] = (_Float16)v1.w;
      const int kc = q >> 4, lh2 = (q >> 3) & 1;
      *(half8*)(W16f + ((size_t)((p * 4 + tc) * 8 + kc)) * 512 + lh2 * 256 + tl * 8) = h;
    }
  } else {
    __shared__ float red4[4];
    float part = 0.f;
#pragma unroll
    for (int i = 0; i < 8; ++i) part += w_red[tid * 8 + i];
#pragma unroll
    for (int off = 32; off > 0; off >>= 1) part += __shfl_down(part, off, 64);
    if ((tid & 63) == 0) red4[tid >> 6] = part;
    __syncthreads();
    const float Sw = red4[0] + red4[1] + red4[2] + red4[3];
    const float br = b_red[0];
    const size_t base = (size_t)(blk - 256) * 1024 + (size_t)tid * 4;
    const int t0 = (int)(base & 127);
    float4 v;
    v.x = Sw * tanhf(b_comp[t0 + 0]) + br;
    v.y = Sw * tanhf(b_comp[t0 + 1]) + br;
    v.z = Sw * tanhf(b_comp[t0 + 2]) + br;
    v.w = Sw * tanhf(b_comp[t0 + 3]) + br;
    *(float4*)(out + base) = v;
  }
}

// ---------------------------------------------------------------------------
// Kernel B: MFMA main, N-split, 2 blocks/CU. 512 blocks:
//   bits{1,2} of blk -> tq (t-quarter, 32 cols); bits{0,3..8} -> mb.
//   XCD = blk&7 -> XCDs {2j,2j+1} read ONLY W16f quarter j (1 MB, L2-deep).
//   Blocks blk and blk+256 (likely same CU) share tq -> shared working set.
// 8 waves = kh 0..7 (16-q chunk each); each wave covers all 4 m-tiles ->
// zero B redundancy; 1 coalesced 1KB B-load + 4 MFMA per p; barrier-free
// p-loop, 3-buffer distance-2 prefetch. acc = 4 x floatx16 = 64 AGPRs.
// LDS 66 KB -> 2 blocks/CU; __launch_bounds__(512,4) forces <=128 regs/wave.
// kh-reduction: parity -> 2 planes, 4 serial phases; inline scatter epilogue.
// v_mfma_f32_32x32x16_f16: A lane m=l&31, k=(l>>5)*8+j; B n=l&31 same k;
// C/D col=l&31, row=(r&3)+8*(r>>2)+4*(l>>5)   [m74/m101-verified]
// ---------------------------------------------------------------------------
__global__ __launch_bounds__(512, 4) void main_kernel(
    const float* __restrict__ tok, const int* __restrict__ heads,
    const _Float16* __restrict__ W16f, const float* __restrict__ b_comp,
    const float* __restrict__ w_red, float* __restrict__ out) {
  __shared__ _Float16 tokT2[128 * TOKR];   // 33.8 KB: [p][(m&31)*4 + (m>>5)]
  __shared__ float red[2][128 * TN];       // 2 x 16 KB: kh-parity planes [m][t_loc]

  const int tid = threadIdx.x;
  const int lane = tid & 63;
  const int kh = tid >> 6;   // wave = q-chunk of 16 (kc index)
  const int l31 = lane & 31;
  const int lh = lane >> 5;
  const int blk = blockIdx.x;
  const int tq = (blk >> 1) & 3;                    // t-quarter, bits{1,2}
  const int mb = ((blk >> 3) << 1) | (blk & 1);     // bits{0,3..8}
  const size_t tokbase = (size_t)mb * BM * T_DIM;

  // ---- stage tokT2: coalesced float4 reads, transposed f16 scalar writes ----
#pragma unroll
  for (int it = 0; it < 8; ++it) {
    const int f = it * 512 + tid;   // 0..4095 float4s over [m(128)][p4(32)]
    const int m = f >> 5;
    const int p0 = (f & 31) * 4;
    const float4 v = *(const float4*)(tok + tokbase + (size_t)m * 128 + p0);
    const int mi = (m & 31) * 4 + (m >> 5);
    tokT2[(p0 + 0) * TOKR + mi] = (_Float16)v.x;
    tokT2[(p0 + 1) * TOKR + mi] = (_Float16)v.y;
    tokT2[(p0 + 2) * TOKR + mi] = (_Float16)v.z;
    tokT2[(p0 + 3) * TOKR + mi] = (_Float16)v.w;
  }

  // ---- per-lane h fragments: h16[mh], q0 = kh*16 + lh*8 ----
  half8 h16[4];
#pragma unroll
  for (int mh = 0; mh < 4; ++mh) {
    const int m = mh * 32 + l31;
    const int q0 = kh * 16 + lh * 8;
    const float4 v0 = *(const float4*)(tok + tokbase + (size_t)m * 128 + q0);
    const float4 v1 = *(const float4*)(tok + tokbase + (size_t)m * 128 + q0 + 4);
    h16[mh][0] = (_Float16)tanhf(v0.x);
    h16[mh][1] = (_Float16)tanhf(v0.y);
    h16[mh][2] = (_Float16)tanhf(v0.z);
    h16[mh][3] = (_Float16)tanhf(v0.w);
    h16[mh][4] = (_Float16)tanhf(v1.x);
    h16[mh][5] = (_Float16)tanhf(v1.y);
    h16[mh][6] = (_Float16)tanhf(v1.z);
    h16[mh][7] = (_Float16)tanhf(v1.w);
  }
  __syncthreads();  // tokT2 ready; last barrier before the p-loop

  // Wave's B-fragment offset within a p-slice: tc = tq, kc = kh
  const int off0 = ((tq * 8 + kh) << 9) + lane * 8;

  floatx16 acc[4];  // [mh] -> 64 AGPRs
#pragma unroll
  for (int mh = 0; mh < 4; ++mh)
#pragma unroll
    for (int r = 0; r < 16; ++r) acc[mh][r] = 0.f;

  half8 bf0, bf1, bf2;

  auto loadB = [&](half8& bf, int p) {
    bf = *(const half8*)(W16f + (size_t)p * 16384 + off0);
  };

  auto compute = [&](half8 bf, int p) {
    const half4 tk = *(const half4*)(tokT2 + p * TOKR + l31 * 4);
    half8 a0 = h16[0] * tk[0];
    half8 a1 = h16[1] * tk[1];
    half8 a2 = h16[2] * tk[2];
    half8 a3 = h16[3] * tk[3];
    acc[0] = __builtin_amdgcn_mfma_f32_32x32x16_f16(a0, bf, acc[0], 0, 0, 0);
    acc[1] = __builtin_amdgcn_mfma_f32_32x32x16_f16(a1, bf, acc[1], 0, 0, 0);
    acc[2] = __builtin_amdgcn_mfma_f32_32x32x16_f16(a2, bf, acc[2], 0, 0, 0);
    acc[3] = __builtin_amdgcn_mfma_f32_32x32x16_f16(a3, bf, acc[3], 0, 0, 0);
  };

  // 3-buffer, distance-2 software pipeline over 128 p (no barriers).
  loadB(bf0, 0);
  loadB(bf1, 1);
  for (int p = 0; p < 126; p += 3) {
    loadB(bf2, p + 2);
    compute(bf0, p);
    loadB(bf0, p + 3);
    compute(bf1, p + 1);
    loadB(bf1, p + 4);
    compute(bf2, p + 2);
  }
  compute(bf0, 126);
  compute(bf1, 127);

  // ---- kh reduction: parity -> plane, 4 serial phases (2 waves/phase) ----
  __syncthreads();
  {
    float* R = &red[kh & 1][0];
    const int g = kh >> 1;  // phase id
#pragma unroll
    for (int phase = 0; phase < 4; ++phase) {
      if (g == phase) {
#pragma unroll
        for (int mh = 0; mh < 4; ++mh)
#pragma unroll
          for (int r = 0; r < 16; ++r) {
            const int m_loc = (r & 3) + 8 * (r >> 2) + 4 * lh;
            const int addr = (mh * 32 + m_loc) * TN + l31;
            if (phase == 0) R[addr] = acc[mh][r];
            else            R[addr] += acc[mh][r];
          }
      }
      __syncthreads();
    }
  }

  // ---- inline scatter epilogue: 512 threads, 8 m's x 1 t each ----
  const int t_loc = tid & 31;
  const int mgrp = tid >> 5;  // 0..15
  const int t = tq * 32 + t_loc;
  const float bc = b_comp[t];
  const float tb = tanhf(bc);
#pragma unroll 4
  for (int mi = 0; mi < 8; ++mi) {
    const int m_loc = mi * 16 + mgrp;
    const int gm = mb * BM + m_loc;
    const int head = heads[gm];
    const float wr = w_red[gm & 2047];
    const float v = red[0][m_loc * TN + t_loc] + red[1][m_loc * TN + t_loc] + bc;
    atomicAdd(out + ((size_t)(gm >> 11) * S_LEN + head) * T_DIM + t,
              wr * (tanhf(v) - tb));
  }
}

// ---------------------------------------------------------------------------
extern "C" void kernel_launch(void* const* d_in, const int* in_sizes, int n_in,
                              void* d_out, int out_size, void* d_ws, size_t ws_size,
                              hipStream_t stream) {
  const float* tok    = (const float*)d_in[0];
  // d_in[1] = dep_embeddings: dead input (source bug), unused
  const int*   heads  = (const int*)d_in[2];
  const float* W      = (const float*)d_in[3];
  const float* b_comp = (const float*)d_in[4];
  const float* w_red  = (const float*)d_in[5];
  const float* b_red  = (const float*)d_in[6];
  float* out = (float*)d_out;

  _Float16* W16f = (_Float16*)d_ws;  // 4 MB, MFMA-fragment order

  prep_kernel<<<2304, 256, 0, stream>>>(W, w_red, b_comp, b_red, W16f, out);
  main_kernel<<<NBLK, 512, 0, stream>>>(tok, heads, W16f, b_comp, w_red, out);
}

// Round 10
// 158.706 us; speedup vs baseline: 2.2148x; 1.0171x over previous
//
#include <hip/hip_runtime.h>
#include <hip/hip_fp16.h>
#include <math.h>

// Problem constants (B=8, S=2048, T=128)
#define S_LEN 2048
#define T_DIM 128
#define BM 128               // tokens per block (m-range)
#define TN 32                // output cols per block
#define NBLK 512             // (mb 0..127) x (tq 0..3), bit-sliced for XCD pinning
#define TOKR 132             // tokT2 row stride in f16

typedef _Float16 half8 __attribute__((ext_vector_type(8)));
typedef _Float16 half4 __attribute__((ext_vector_type(4)));
typedef float floatx16 __attribute__((ext_vector_type(16)));

// ---------------------------------------------------------------------------
// Kernel A (grid 2304x256): fused prep, independent block ranges:
//  blocks 0..255   : W fp32 [t][p][q] -> W16f fp16 MFMA-fragment order
//    W16f[((p*4 + tc)*8 + kc)*512 + lh2*256 + (t&31)*8 + j],
//    tc=t>>5, kc=q>>4, lh2=(q>>3)&1, j=q&7
//  blocks 256..2303: out[b,i,t] = sum(w_red)*tanh(b_comp[t]) + b_red
// ---------------------------------------------------------------------------
__global__ __launch_bounds__(256) void prep_kernel(
    const float* __restrict__ W, const float* __restrict__ w_red,
    const float* __restrict__ b_comp, const float* __restrict__ b_red,
    _Float16* __restrict__ W16f, float* __restrict__ out) {
  const int blk = blockIdx.x;
  const int tid = threadIdx.x;
  if (blk < 256) {
    const int t = blk >> 1, qh = blk & 1;
    const int tc = t >> 5, tl = t & 31;
#pragma unroll
    for (int it = 0; it < 4; ++it) {
      const int e8 = it * 256 + tid;        // 0..1023 over [p(128)][q-chunk(8)]
      const int p = e8 >> 3;
      const int q = qh * 64 + (e8 & 7) * 8;
      const float* src = W + (size_t)t * 16384 + (size_t)p * 128 + q;
      const float4 v0 = *(const float4*)src;
      const float4 v1 = *(const float4*)(src + 4);
      half8 h;
      h[0] = (_Float16)v0.x; h[1] = (_Float16)v0.y;
      h[2] = (_Float16)v0.z; h[3] = (_Float16)v0.w;
      h[4] = (_Float16)v1.x; h[5] = (_Float16)v1.y;
      h[6] = (_Float16)v1.z; h[7] = (_Float16)v1.w;
      const int kc = q >> 4, lh2 = (q >> 3) & 1;
      *(half8*)(W16f + ((size_t)((p * 4 + tc) * 8 + kc)) * 512 + lh2 * 256 + tl * 8) = h;
    }
  } else {
    __shared__ float red4[4];
    float part = 0.f;
#pragma unroll
    for (int i = 0; i < 8; ++i) part += w_red[tid * 8 + i];
#pragma unroll
    for (int off = 32; off > 0; off >>= 1) part += __shfl_down(part, off, 64);
    if ((tid & 63) == 0) red4[tid >> 6] = part;
    __syncthreads();
    const float Sw = red4[0] + red4[1] + red4[2] + red4[3];
    const float br = b_red[0];
    const size_t base = (size_t)(blk - 256) * 1024 + (size_t)tid * 4;
    const int t0 = (int)(base & 127);
    float4 v;
    v.x = Sw * tanhf(b_comp[t0 + 0]) + br;
    v.y = Sw * tanhf(b_comp[t0 + 1]) + br;
    v.z = Sw * tanhf(b_comp[t0 + 2]) + br;
    v.w = Sw * tanhf(b_comp[t0 + 3]) + br;
    *(float4*)(out + base) = v;
  }
}

// ---------------------------------------------------------------------------
// Kernel B: MFMA main, N-split, 2 blocks/CU (identical structure to R9).
// CHANGE vs R9: the tk (tokT2) LDS read is software-pipelined distance-2 in
// registers alongside the B prefetch, removing the ~120-cyc ds_read latency
// previously exposed at the head of every p-iteration (all waves in lockstep).
// v_mfma_f32_32x32x16_f16: A lane m=l&31, k=(l>>5)*8+j; B n=l&31 same k;
// C/D col=l&31, row=(r&3)+8*(r>>2)+4*(l>>5)   [m74/m101-verified]
// ---------------------------------------------------------------------------
__global__ __launch_bounds__(512, 4) void main_kernel(
    const float* __restrict__ tok, const int* __restrict__ heads,
    const _Float16* __restrict__ W16f, const float* __restrict__ b_comp,
    const float* __restrict__ w_red, float* __restrict__ out) {
  __shared__ _Float16 tokT2[128 * TOKR];   // 33.8 KB: [p][(m&31)*4 + (m>>5)]
  __shared__ float red[2][128 * TN];       // 2 x 16 KB: kh-parity planes [m][t_loc]

  const int tid = threadIdx.x;
  const int lane = tid & 63;
  const int kh = tid >> 6;   // wave = q-chunk of 16 (kc index)
  const int l31 = lane & 31;
  const int lh = lane >> 5;
  const int blk = blockIdx.x;
  const int tq = (blk >> 1) & 3;                    // t-quarter, bits{1,2}
  const int mb = ((blk >> 3) << 1) | (blk & 1);     // bits{0,3..8}
  const size_t tokbase = (size_t)mb * BM * T_DIM;

  // ---- stage tokT2: coalesced float4 reads, transposed f16 scalar writes ----
#pragma unroll
  for (int it = 0; it < 8; ++it) {
    const int f = it * 512 + tid;   // 0..4095 float4s over [m(128)][p4(32)]
    const int m = f >> 5;
    const int p0 = (f & 31) * 4;
    const float4 v = *(const float4*)(tok + tokbase + (size_t)m * 128 + p0);
    const int mi = (m & 31) * 4 + (m >> 5);
    tokT2[(p0 + 0) * TOKR + mi] = (_Float16)v.x;
    tokT2[(p0 + 1) * TOKR + mi] = (_Float16)v.y;
    tokT2[(p0 + 2) * TOKR + mi] = (_Float16)v.z;
    tokT2[(p0 + 3) * TOKR + mi] = (_Float16)v.w;
  }

  // ---- per-lane h fragments: h16[mh], q0 = kh*16 + lh*8 ----
  half8 h16[4];
#pragma unroll
  for (int mh = 0; mh < 4; ++mh) {
    const int m = mh * 32 + l31;
    const int q0 = kh * 16 + lh * 8;
    const float4 v0 = *(const float4*)(tok + tokbase + (size_t)m * 128 + q0);
    const float4 v1 = *(const float4*)(tok + tokbase + (size_t)m * 128 + q0 + 4);
    h16[mh][0] = (_Float16)tanhf(v0.x);
    h16[mh][1] = (_Float16)tanhf(v0.y);
    h16[mh][2] = (_Float16)tanhf(v0.z);
    h16[mh][3] = (_Float16)tanhf(v0.w);
    h16[mh][4] = (_Float16)tanhf(v1.x);
    h16[mh][5] = (_Float16)tanhf(v1.y);
    h16[mh][6] = (_Float16)tanhf(v1.z);
    h16[mh][7] = (_Float16)tanhf(v1.w);
  }
  __syncthreads();  // tokT2 ready; last barrier before the p-loop

  // Wave's B-fragment offset within a p-slice: tc = tq, kc = kh
  const int off0 = ((tq * 8 + kh) << 9) + lane * 8;

  floatx16 acc[4];  // [mh] -> 64 AGPRs
#pragma unroll
  for (int mh = 0; mh < 4; ++mh)
#pragma unroll
    for (int r = 0; r < 16; ++r) acc[mh][r] = 0.f;

  half8 bf0, bf1, bf2;
  half4 tk0, tk1, tk2;

  auto loadB = [&](half8& bf, int p) {
    bf = *(const half8*)(W16f + (size_t)p * 16384 + off0);
  };
  auto loadT = [&](half4& tk, int p) {
    tk = *(const half4*)(tokT2 + p * TOKR + l31 * 4);
  };

  auto compute = [&](half8 bf, half4 tk) {
    half8 a0 = h16[0] * tk[0];
    half8 a1 = h16[1] * tk[1];
    half8 a2 = h16[2] * tk[2];
    half8 a3 = h16[3] * tk[3];
    acc[0] = __builtin_amdgcn_mfma_f32_32x32x16_f16(a0, bf, acc[0], 0, 0, 0);
    acc[1] = __builtin_amdgcn_mfma_f32_32x32x16_f16(a1, bf, acc[1], 0, 0, 0);
    acc[2] = __builtin_amdgcn_mfma_f32_32x32x16_f16(a2, bf, acc[2], 0, 0, 0);
    acc[3] = __builtin_amdgcn_mfma_f32_32x32x16_f16(a3, bf, acc[3], 0, 0, 0);
  };

  // 3-buffer, distance-2 software pipeline over 128 p (no barriers);
  // BOTH the B-fragment (global/L2) and tk (LDS) loads run 2 iters ahead.
  loadB(bf0, 0);  loadT(tk0, 0);
  loadB(bf1, 1);  loadT(tk1, 1);
  for (int p = 0; p < 126; p += 3) {
    loadB(bf2, p + 2);  loadT(tk2, p + 2);
    compute(bf0, tk0);
    loadB(bf0, p + 3);  loadT(tk0, p + 3);
    compute(bf1, tk1);
    loadB(bf1, p + 4);  loadT(tk1, p + 4);
    compute(bf2, tk2);
  }
  compute(bf0, tk0);  // p = 126
  compute(bf1, tk1);  // p = 127

  // ---- kh reduction: parity -> plane, 4 serial phases (2 waves/phase) ----
  __syncthreads();
  {
    float* R = &red[kh & 1][0];
    const int g = kh >> 1;  // phase id
#pragma unroll
    for (int phase = 0; phase < 4; ++phase) {
      if (g == phase) {
#pragma unroll
        for (int mh = 0; mh < 4; ++mh)
#pragma unroll
          for (int r = 0; r < 16; ++r) {
            const int m_loc = (r & 3) + 8 * (r >> 2) + 4 * lh;
            const int addr = (mh * 32 + m_loc) * TN + l31;
            if (phase == 0) R[addr] = acc[mh][r];
            else            R[addr] += acc[mh][r];
          }
      }
      __syncthreads();
    }
  }

  // ---- inline scatter epilogue: 512 threads, 8 m's x 1 t each ----
  const int t_loc = tid & 31;
  const int mgrp = tid >> 5;  // 0..15
  const int t = tq * 32 + t_loc;
  const float bc = b_comp[t];
  const float tb = tanhf(bc);
#pragma unroll 4
  for (int mi = 0; mi < 8; ++mi) {
    const int m_loc = mi * 16 + mgrp;
    const int gm = mb * BM + m_loc;
    const int head = heads[gm];
    const float wr = w_red[gm & 2047];
    const float v = red[0][m_loc * TN + t_loc] + red[1][m_loc * TN + t_loc] + bc;
    atomicAdd(out + ((size_t)(gm >> 11) * S_LEN + head) * T_DIM + t,
              wr * (tanhf(v) - tb));
  }
}

// ---------------------------------------------------------------------------
extern "C" void kernel_launch(void* const* d_in, const int* in_sizes, int n_in,
                              void* d_out, int out_size, void* d_ws, size_t ws_size,
                              hipStream_t stream) {
  const float* tok    = (const float*)d_in[0];
  // d_in[1] = dep_embeddings: dead input (source bug), unused
  const int*   heads  = (const int*)d_in[2];
  const float* W      = (const float*)d_in[3];
  const float* b_comp = (const float*)d_in[4];
  const float* w_red  = (const float*)d_in[5];
  const float* b_red  = (const float*)d_in[6];
  float* out = (float*)d_out;

  _Float16* W16f = (_Float16*)d_ws;  // 4 MB, MFMA-fragment order

  prep_kernel<<<2304, 256, 0, stream>>>(W, w_red, b_comp, b_red, W16f, out);
  main_kernel<<<NBLK, 512, 0, stream>>>(tok, heads, W16f, b_comp, w_red, out);
}